// Round 1
// baseline (118.664 us; speedup 1.0000x reference)
//
#include <hip/hip_runtime.h>
#include <cstdint>
#include <cstddef>

// ---------------- problem constants ----------------
#define GXD 512
#define GYD 512
#define GZD 15
#define NVOX (GXD * GYD * GZD)   // 3,932,160
#define NWORDS (NVOX / 64)       // 61,440
#define MAXV 120000
#define MAXP 32

#define VOX_FLOATS (MAXV * MAXP * 3)     // 11,520,000
#define COORS_OFF  VOX_FLOATS            // coors start (float-encoded ints)
#define NP_OFF     (VOX_FLOATS + MAXV*3) // 11,880,000
#define OUT_TOTAL  (NP_OFF + MAXV)       // 12,000,000

// ---------------- workspace layout (bytes) ----------------
// bitmask u64[NWORDS]           @ 0        (491,520 B)
// wordPrefix u32[NWORDS]        @ 491,520  (245,760 B)
// blockSums u32[64]             @ 737,280
// blockOffsets u32[64]          @ 737,536
// cursors u32[MAXV]             @ 737,792  (480,000 B)  -> total 1,217,792 B
#define WP_OFF_B   (NWORDS * 8)
#define BS_OFF_B   (WP_OFF_B + NWORDS * 4)
#define BO_OFF_B   (BS_OFF_B + 256)
#define CUR_OFF_B  (BO_OFF_B + 256)
#define WS_BYTES   (CUR_OFF_B + MAXV * 4)

// lin -> coords:  GX*GY = 2^18, GX = 2^9
__device__ __forceinline__ int compute_lin(float x, float y, float z) {
    if (isnan(x) || isnan(y) || isnan(z)) return -1;
    // EXACT reference numerics: f32 subtract, f32 IEEE divide, floorf
    float cxf = floorf((x - (-51.2f)) / 0.2f);
    float cyf = floorf((y - (-51.2f)) / 0.2f);
    float czf = floorf((z - (-3.0f)) / 0.4f);
    if (!(cxf >= 0.0f && cxf < 512.0f &&
          cyf >= 0.0f && cyf < 512.0f &&
          czf >= 0.0f && czf < 15.0f)) return -1;
    int cx = (int)cxf, cy = (int)cyf, cz = (int)czf;
    return (cz << 18) + (cy << 9) + cx;
}

// ---------------- kernels ----------------
__global__ void k_zero_ws(uint32_t* __restrict__ ws, int n) {
    int i = blockIdx.x * blockDim.x + threadIdx.x;
    int stride = gridDim.x * blockDim.x;
    for (; i < n; i += stride) ws[i] = 0u;
}

__global__ void k_init_out(float* __restrict__ out) {
    int i = blockIdx.x * blockDim.x + threadIdx.x;
    int stride = gridDim.x * blockDim.x;
    for (; i < OUT_TOTAL; i += stride) {
        float v = 0.0f;
        if (i >= COORS_OFF && i < NP_OFF) v = -1.0f;  // coors default
        out[i] = v;
    }
}

__global__ void k_bin(const float* __restrict__ pts, int P,
                      unsigned long long* __restrict__ bm) {
    int i = blockIdx.x * blockDim.x + threadIdx.x;
    if (i >= P) return;
    float x = pts[3*i], y = pts[3*i+1], z = pts[3*i+2];
    int lin = compute_lin(x, y, z);
    if (lin < 0) return;
    atomicOr(&bm[lin >> 6], 1ull << (lin & 63));
}

// 60 blocks x 256 threads, 4 words/thread (1024 words/block)
__global__ void k_scan1(const unsigned long long* __restrict__ bm,
                        uint32_t* __restrict__ blockSums) {
    __shared__ uint32_t sh[256];
    int t = threadIdx.x, b = blockIdx.x;
    int base = b * 1024 + t * 4;
    uint32_t s = 0;
#pragma unroll
    for (int k = 0; k < 4; ++k) s += (uint32_t)__popcll(bm[base + k]);
    sh[t] = s; __syncthreads();
    for (int off = 128; off > 0; off >>= 1) {
        if (t < off) sh[t] += sh[t + off];
        __syncthreads();
    }
    if (t == 0) blockSums[b] = sh[0];
}

// single wave: exclusive scan of 60 block sums
__global__ void k_scan2(const uint32_t* __restrict__ blockSums,
                        uint32_t* __restrict__ blockOffsets) {
    int t = threadIdx.x;  // 64 threads
    uint32_t own = (t < 60) ? blockSums[t] : 0u;
    uint32_t v = own;
    for (int off = 1; off < 64; off <<= 1) {
        uint32_t n = __shfl_up(v, off, 64);
        if (t >= off) v += n;
    }
    if (t < 60) blockOffsets[t] = v - own;  // exclusive
}

__global__ void k_scan3(const unsigned long long* __restrict__ bm,
                        const uint32_t* __restrict__ blockOffsets,
                        uint32_t* __restrict__ wordPrefix) {
    __shared__ uint32_t sh[256];
    int t = threadIdx.x, b = blockIdx.x;
    int base = b * 1024 + t * 4;
    uint32_t c0 = (uint32_t)__popcll(bm[base + 0]);
    uint32_t c1 = (uint32_t)__popcll(bm[base + 1]);
    uint32_t c2 = (uint32_t)__popcll(bm[base + 2]);
    uint32_t c3 = (uint32_t)__popcll(bm[base + 3]);
    uint32_t s = c0 + c1 + c2 + c3;
    sh[t] = s; __syncthreads();
    // Hillis-Steele inclusive scan over 256 thread sums
    for (int off = 1; off < 256; off <<= 1) {
        uint32_t v = (t >= off) ? sh[t - off] : 0u;
        __syncthreads();
        sh[t] += v;
        __syncthreads();
    }
    uint32_t excl = sh[t] - s + blockOffsets[b];
    wordPrefix[base + 0] = excl;
    wordPrefix[base + 1] = excl + c0;
    wordPrefix[base + 2] = excl + c0 + c1;
    wordPrefix[base + 3] = excl + c0 + c1 + c2;
}

__global__ void k_emit(const float* __restrict__ pts, int P,
                       const unsigned long long* __restrict__ bm,
                       const uint32_t* __restrict__ wordPrefix,
                       uint32_t* __restrict__ cursors,
                       float* __restrict__ out) {
    int i = blockIdx.x * blockDim.x + threadIdx.x;
    if (i >= P) return;
    float x = pts[3*i], y = pts[3*i+1], z = pts[3*i+2];
    int lin = compute_lin(x, y, z);
    if (lin < 0) return;
    int w = lin >> 6, bit = lin & 63;
    unsigned long long mask = bm[w];
    uint32_t slot = wordPrefix[w] +
                    (uint32_t)__popcll(mask & ((1ull << bit) - 1ull));
    if (slot >= MAXV) return;   // only the 120000 smallest-lin voxels kept
    uint32_t r = atomicAdd(&cursors[slot], 1u);
    if (r < MAXP) {
        float* vp = out + (size_t)slot * (MAXP * 3) + (size_t)r * 3;
        vp[0] = x; vp[1] = y; vp[2] = z;
    }
    if (r == 0) {
        int cz = lin >> 18, cy = (lin >> 9) & 511, cx = lin & 511;
        float* cp = out + COORS_OFF + (size_t)slot * 3;
        cp[0] = (float)cz; cp[1] = (float)cy; cp[2] = (float)cx;  // (z,y,x)
    }
}

__global__ void k_numpoints(const uint32_t* __restrict__ cursors,
                            float* __restrict__ out) {
    int v = blockIdx.x * blockDim.x + threadIdx.x;
    if (v >= MAXV) return;
    uint32_t c = cursors[v];
    if (c > MAXP) c = MAXP;
    out[NP_OFF + v] = (float)c;
}

// ---------------- launch ----------------
extern "C" void kernel_launch(void* const* d_in, const int* in_sizes, int n_in,
                              void* d_out, int out_size, void* d_ws, size_t ws_size,
                              hipStream_t stream) {
    const float* pts = (const float*)d_in[0];
    const int P = in_sizes[0] / 3;  // 2,097,152
    float* out = (float*)d_out;

    char* ws = (char*)d_ws;
    unsigned long long* bm = (unsigned long long*)(ws + 0);
    uint32_t* wordPrefix   = (uint32_t*)(ws + WP_OFF_B);
    uint32_t* blockSums    = (uint32_t*)(ws + BS_OFF_B);
    uint32_t* blockOffsets = (uint32_t*)(ws + BO_OFF_B);
    uint32_t* cursors      = (uint32_t*)(ws + CUR_OFF_B);

    const int nZero = WS_BYTES / 4;  // zero entire ws region we use

    k_zero_ws<<<1024, 256, 0, stream>>>((uint32_t*)d_ws, nZero);
    k_init_out<<<2048, 256, 0, stream>>>(out);
    k_bin<<<(P + 255) / 256, 256, 0, stream>>>(pts, P, bm);
    k_scan1<<<NWORDS / 1024, 256, 0, stream>>>(bm, blockSums);
    k_scan2<<<1, 64, 0, stream>>>(blockSums, blockOffsets);
    k_scan3<<<NWORDS / 1024, 256, 0, stream>>>(bm, blockOffsets, wordPrefix);
    k_emit<<<(P + 255) / 256, 256, 0, stream>>>(pts, P, bm, wordPrefix, cursors, out);
    k_numpoints<<<(MAXV + 255) / 256, 256, 0, stream>>>(cursors, out);
}

// Round 2
// 77.056 us; speedup vs baseline: 1.5400x; 1.5400x over previous
//
#include <hip/hip_runtime.h>
#include <cstdint>
#include <cstddef>

// ---------------- problem constants ----------------
#define GXD 512
#define GYD 512
#define GZD 15
#define NVOX (GXD * GYD * GZD)   // 3,932,160
#define NWORDS (NVOX / 64)       // 61,440
#define MAXV 120000
#define MAXP 32

#define VOX_FLOATS (MAXV * MAXP * 3)     // 11,520,000
#define COORS_OFF  VOX_FLOATS            // coors start (float-encoded ints)
#define NP_OFF     (VOX_FLOATS + MAXV*3) // 11,880,000
#define OUT_TOTAL  (NP_OFF + MAXV)       // 12,000,000

// ---------------- workspace layout (bytes), byte-mask path ----------------
// byteMask u8[NVOX]   @ 0          (3,932,160 B)
// bm u64[NWORDS]      @ NVOX       (491,520 B)
// wordPrefix u32[...] @ +          (245,760 B)
// blockSums/Offsets   @ +          (512 B)
// cursors u32[MAXV]   @ +          (480,000 B)
#define BM_OFF_B   NVOX
#define WP_OFF_B   (BM_OFF_B + NWORDS * 8)
#define BS_OFF_B   (WP_OFF_B + NWORDS * 4)
#define BO_OFF_B   (BS_OFF_B + 256)
#define CUR_OFF_B  (BO_OFF_B + 256)
#define WS_BYTES   (CUR_OFF_B + MAXV * 4)   // ~5.15 MB

// fallback layout (atomic path, no byte array)
#define FB_WP_OFF_B   (NWORDS * 8)
#define FB_BS_OFF_B   (FB_WP_OFF_B + NWORDS * 4)
#define FB_BO_OFF_B   (FB_BS_OFF_B + 256)
#define FB_CUR_OFF_B  (FB_BO_OFF_B + 256)

// lin -> coords:  GX*GY = 2^18, GX = 2^9
__device__ __forceinline__ int compute_lin(float x, float y, float z) {
    if (isnan(x) || isnan(y) || isnan(z)) return -1;
    // EXACT reference numerics: f32 subtract, f32 IEEE divide, floorf
    float cxf = floorf((x - (-51.2f)) / 0.2f);
    float cyf = floorf((y - (-51.2f)) / 0.2f);
    float czf = floorf((z - (-3.0f)) / 0.4f);
    if (!(cxf >= 0.0f && cxf < 512.0f &&
          cyf >= 0.0f && cyf < 512.0f &&
          czf >= 0.0f && czf < 15.0f)) return -1;
    int cx = (int)cxf, cy = (int)cyf, cz = (int)czf;
    return (cz << 18) + (cy << 9) + cx;
}

// ---------------- init kernels ----------------
__global__ void k_zero2(uint32_t* __restrict__ a, int na,
                        uint32_t* __restrict__ b, int nb) {
    int i = blockIdx.x * blockDim.x + threadIdx.x;
    int stride = gridDim.x * blockDim.x;
    for (int j = i; j < na; j += stride) a[j] = 0u;
    for (int j = i; j < nb; j += stride) b[j] = 0u;
}

__global__ void k_init_out(float4* __restrict__ out4) {
    int i = blockIdx.x * blockDim.x + threadIdx.x;
    int stride = gridDim.x * blockDim.x;
    const int n  = OUT_TOTAL / 4;
    const int c0 = COORS_OFF / 4, c1 = NP_OFF / 4;
    for (; i < n; i += stride) {
        float v = (i >= c0 && i < c1) ? -1.0f : 0.0f;
        out4[i] = make_float4(v, v, v, v);
    }
}

// ---------------- mark: plain byte stores (no atomics) ----------------
__device__ __forceinline__ void mark_one(float x, float y, float z,
                                         uint8_t* __restrict__ bytes) {
    int lin = compute_lin(x, y, z);
    if (lin >= 0) bytes[lin] = 1;
}

__global__ void k_mark(const float* __restrict__ pts, int P,
                       uint8_t* __restrict__ bytes) {
    int tid = blockIdx.x * blockDim.x + threadIdx.x;
    int base = tid * 4;
    if (base + 3 < P) {
        const float4* p4 = (const float4*)pts;
        float4 a = p4[tid * 3 + 0];
        float4 b = p4[tid * 3 + 1];
        float4 c = p4[tid * 3 + 2];
        mark_one(a.x, a.y, a.z, bytes);
        mark_one(a.w, b.x, b.y, bytes);
        mark_one(b.z, b.w, c.x, bytes);
        mark_one(c.y, c.z, c.w, bytes);
    } else {
        for (int i = base; i < P; ++i)
            mark_one(pts[3*i], pts[3*i+1], pts[3*i+2], bytes);
    }
}

// fallback: atomicOr binning (used only if ws too small for byte mask)
__global__ void k_bin(const float* __restrict__ pts, int P,
                      unsigned long long* __restrict__ bm) {
    int i = blockIdx.x * blockDim.x + threadIdx.x;
    if (i >= P) return;
    int lin = compute_lin(pts[3*i], pts[3*i+1], pts[3*i+2]);
    if (lin < 0) return;
    atomicOr(&bm[lin >> 6], 1ull << (lin & 63));
}

// ---------------- pack bytes -> bitmask, fused with block sums ----------------
// 60 blocks x 256 threads, 4 words (=256 bytes) per thread
__global__ void k_pack(const uint8_t* __restrict__ bytes,
                       unsigned long long* __restrict__ bm,
                       uint32_t* __restrict__ blockSums) {
    __shared__ uint32_t sh[256];
    int t = threadIdx.x, b = blockIdx.x;
    int w0 = b * 1024 + t * 4;
    const unsigned long long* b64 = (const unsigned long long*)bytes;
    uint32_t s = 0;
#pragma unroll
    for (int k = 0; k < 4; ++k) {
        int w = w0 + k;
        unsigned long long word = 0;
#pragma unroll
        for (int j = 0; j < 8; ++j) {
            unsigned long long v = b64[w * 8 + j];   // 8 bytes, each 0 or 1
            // carry-free pack: bit(56+i) of v*M == byte i   (M = sum 2^(56-7j))
            unsigned long long m = (v * 0x0102040810204080ull) >> 56;
            word |= m << (8 * j);
        }
        bm[w] = word;
        s += (uint32_t)__popcll(word);
    }
    sh[t] = s; __syncthreads();
    for (int off = 128; off > 0; off >>= 1) {
        if (t < off) sh[t] += sh[t + off];
        __syncthreads();
    }
    if (t == 0) blockSums[b] = sh[0];
}

// fallback scan1 (reads bm directly)
__global__ void k_scan1(const unsigned long long* __restrict__ bm,
                        uint32_t* __restrict__ blockSums) {
    __shared__ uint32_t sh[256];
    int t = threadIdx.x, b = blockIdx.x;
    int base = b * 1024 + t * 4;
    uint32_t s = 0;
#pragma unroll
    for (int k = 0; k < 4; ++k) s += (uint32_t)__popcll(bm[base + k]);
    sh[t] = s; __syncthreads();
    for (int off = 128; off > 0; off >>= 1) {
        if (t < off) sh[t] += sh[t + off];
        __syncthreads();
    }
    if (t == 0) blockSums[b] = sh[0];
}

// single wave: exclusive scan of 60 block sums
__global__ void k_scan2(const uint32_t* __restrict__ blockSums,
                        uint32_t* __restrict__ blockOffsets) {
    int t = threadIdx.x;  // 64 threads
    uint32_t own = (t < 60) ? blockSums[t] : 0u;
    uint32_t v = own;
    for (int off = 1; off < 64; off <<= 1) {
        uint32_t n = __shfl_up(v, off, 64);
        if (t >= off) v += n;
    }
    if (t < 60) blockOffsets[t] = v - own;  // exclusive
}

__global__ void k_scan3(const unsigned long long* __restrict__ bm,
                        const uint32_t* __restrict__ blockOffsets,
                        uint32_t* __restrict__ wordPrefix) {
    __shared__ uint32_t sh[256];
    int t = threadIdx.x, b = blockIdx.x;
    int base = b * 1024 + t * 4;
    uint32_t c0 = (uint32_t)__popcll(bm[base + 0]);
    uint32_t c1 = (uint32_t)__popcll(bm[base + 1]);
    uint32_t c2 = (uint32_t)__popcll(bm[base + 2]);
    uint32_t c3 = (uint32_t)__popcll(bm[base + 3]);
    uint32_t s = c0 + c1 + c2 + c3;
    sh[t] = s; __syncthreads();
    for (int off = 1; off < 256; off <<= 1) {
        uint32_t v = (t >= off) ? sh[t - off] : 0u;
        __syncthreads();
        sh[t] += v;
        __syncthreads();
    }
    uint32_t excl = sh[t] - s + blockOffsets[b];
    wordPrefix[base + 0] = excl;
    wordPrefix[base + 1] = excl + c0;
    wordPrefix[base + 2] = excl + c0 + c1;
    wordPrefix[base + 3] = excl + c0 + c1 + c2;
}

// ---------------- emit ----------------
__device__ __forceinline__ void emit_one(float x, float y, float z,
                                         const unsigned long long* __restrict__ bm,
                                         const uint32_t* __restrict__ wordPrefix,
                                         uint32_t* __restrict__ cursors,
                                         float* __restrict__ out) {
    int lin = compute_lin(x, y, z);
    if (lin < 0) return;
    int w = lin >> 6, bit = lin & 63;
    unsigned long long mask = bm[w];
    uint32_t slot = wordPrefix[w] +
                    (uint32_t)__popcll(mask & ((1ull << bit) - 1ull));
    if (slot >= MAXV) return;   // only the 120000 smallest-lin voxels kept
    uint32_t r = atomicAdd(&cursors[slot], 1u);
    if (r < MAXP) {
        float* vp = out + (size_t)slot * (MAXP * 3) + (size_t)r * 3;
        vp[0] = x; vp[1] = y; vp[2] = z;
    }
    if (r == 0) {
        int cz = lin >> 18, cy = (lin >> 9) & 511, cx = lin & 511;
        float* cp = out + COORS_OFF + (size_t)slot * 3;
        cp[0] = (float)cz; cp[1] = (float)cy; cp[2] = (float)cx;  // (z,y,x)
    }
}

__global__ void k_emit(const float* __restrict__ pts, int P,
                       const unsigned long long* __restrict__ bm,
                       const uint32_t* __restrict__ wordPrefix,
                       uint32_t* __restrict__ cursors,
                       float* __restrict__ out) {
    int tid = blockIdx.x * blockDim.x + threadIdx.x;
    int base = tid * 4;
    if (base + 3 < P) {
        const float4* p4 = (const float4*)pts;
        float4 a = p4[tid * 3 + 0];
        float4 b = p4[tid * 3 + 1];
        float4 c = p4[tid * 3 + 2];
        emit_one(a.x, a.y, a.z, bm, wordPrefix, cursors, out);
        emit_one(a.w, b.x, b.y, bm, wordPrefix, cursors, out);
        emit_one(b.z, b.w, c.x, bm, wordPrefix, cursors, out);
        emit_one(c.y, c.z, c.w, bm, wordPrefix, cursors, out);
    } else {
        for (int i = base; i < P; ++i)
            emit_one(pts[3*i], pts[3*i+1], pts[3*i+2],
                     bm, wordPrefix, cursors, out);
    }
}

__global__ void k_numpoints(const uint32_t* __restrict__ cursors,
                            float* __restrict__ out) {
    int v = blockIdx.x * blockDim.x + threadIdx.x;
    if (v >= MAXV) return;
    uint32_t c = cursors[v];
    if (c > MAXP) c = MAXP;
    out[NP_OFF + v] = (float)c;
}

// ---------------- launch ----------------
extern "C" void kernel_launch(void* const* d_in, const int* in_sizes, int n_in,
                              void* d_out, int out_size, void* d_ws, size_t ws_size,
                              hipStream_t stream) {
    const float* pts = (const float*)d_in[0];
    const int P = in_sizes[0] / 3;  // 2,097,152
    float* out = (float*)d_out;
    char* ws = (char*)d_ws;

    const int ptThreads = (P + 3) / 4;
    const int ptBlocks  = (ptThreads + 255) / 256;

    if (ws_size >= (size_t)WS_BYTES) {
        uint8_t* bytes             = (uint8_t*)(ws + 0);
        unsigned long long* bm     = (unsigned long long*)(ws + BM_OFF_B);
        uint32_t* wordPrefix       = (uint32_t*)(ws + WP_OFF_B);
        uint32_t* blockSums        = (uint32_t*)(ws + BS_OFF_B);
        uint32_t* blockOffsets     = (uint32_t*)(ws + BO_OFF_B);
        uint32_t* cursors          = (uint32_t*)(ws + CUR_OFF_B);

        k_zero2<<<1024, 256, 0, stream>>>((uint32_t*)bytes, NVOX / 4,
                                          cursors, MAXV);
        k_init_out<<<2048, 256, 0, stream>>>((float4*)out);
        k_mark<<<ptBlocks, 256, 0, stream>>>(pts, P, bytes);
        k_pack<<<NWORDS / 1024, 256, 0, stream>>>(bytes, bm, blockSums);
        k_scan2<<<1, 64, 0, stream>>>(blockSums, blockOffsets);
        k_scan3<<<NWORDS / 1024, 256, 0, stream>>>(bm, blockOffsets, wordPrefix);
        k_emit<<<ptBlocks, 256, 0, stream>>>(pts, P, bm, wordPrefix, cursors, out);
        k_numpoints<<<(MAXV + 255) / 256, 256, 0, stream>>>(cursors, out);
    } else {
        // fallback: atomic binning path (smaller ws footprint)
        unsigned long long* bm     = (unsigned long long*)(ws + 0);
        uint32_t* wordPrefix       = (uint32_t*)(ws + FB_WP_OFF_B);
        uint32_t* blockSums        = (uint32_t*)(ws + FB_BS_OFF_B);
        uint32_t* blockOffsets     = (uint32_t*)(ws + FB_BO_OFF_B);
        uint32_t* cursors          = (uint32_t*)(ws + FB_CUR_OFF_B);

        k_zero2<<<1024, 256, 0, stream>>>((uint32_t*)bm, NWORDS * 2,
                                          cursors, MAXV);
        k_init_out<<<2048, 256, 0, stream>>>((float4*)out);
        k_bin<<<(P + 255) / 256, 256, 0, stream>>>(pts, P, bm);
        k_scan1<<<NWORDS / 1024, 256, 0, stream>>>(bm, blockSums);
        k_scan2<<<1, 64, 0, stream>>>(blockSums, blockOffsets);
        k_scan3<<<NWORDS / 1024, 256, 0, stream>>>(bm, blockOffsets, wordPrefix);
        k_emit<<<ptBlocks, 256, 0, stream>>>(pts, P, bm, wordPrefix, cursors, out);
        k_numpoints<<<(MAXV + 255) / 256, 256, 0, stream>>>(cursors, out);
    }
}

// Round 3
// 66.933 us; speedup vs baseline: 1.7729x; 1.1512x over previous
//
#include <hip/hip_runtime.h>
#include <cstdint>
#include <cstddef>

// ---------------- problem constants ----------------
#define GXD 512
#define GYD 512
#define GZD 15
#define NVOX (GXD * GYD * GZD)   // 3,932,160
#define NWORDS (NVOX / 64)       // 61,440
#define NBLKS  60                // NWORDS / 1024
#define MAXV 120000
#define MAXP 32

#define VOX_FLOATS (MAXV * MAXP * 3)     // 11,520,000
#define COORS_OFF  VOX_FLOATS
#define NP_OFF     (VOX_FLOATS + MAXV*3) // 11,880,000
#define OUT_TOTAL  (NP_OFF + MAXV)       // 12,000,000

// ---------------- workspace layout (bytes) ----------------
// byteMask u8[NVOX]      @ 0
// bm u64[NWORDS]         @ NVOX
// blockSums u32[64]      @ +
// wordInfo uint4[NWORDS] @ +   ({word_lo, word_hi, prefix, pad})
// cursors u32[MAXV]      @ +
#define BM_OFF_B   NVOX                      // 3,932,160
#define BS_OFF_B   (BM_OFF_B + NWORDS * 8)   // 4,423,680
#define WI_OFF_B   (BS_OFF_B + 256)          // 4,423,936
#define CUR_OFF_B  (WI_OFF_B + NWORDS * 16)  // 5,406,976
#define WS_BYTES   (CUR_OFF_B + MAXV * 4)    // ~5.9 MB

// lin -> coords:  GX*GY = 2^18, GX = 2^9
__device__ __forceinline__ int compute_lin(float x, float y, float z) {
    if (isnan(x) || isnan(y) || isnan(z)) return -1;
    // EXACT reference numerics: f32 subtract, f32 IEEE divide, floorf
    float cxf = floorf((x - (-51.2f)) / 0.2f);
    float cyf = floorf((y - (-51.2f)) / 0.2f);
    float czf = floorf((z - (-3.0f)) / 0.4f);
    if (!(cxf >= 0.0f && cxf < 512.0f &&
          cyf >= 0.0f && cyf < 512.0f &&
          czf >= 0.0f && czf < 15.0f)) return -1;
    int cx = (int)cxf, cy = (int)cyf, cz = (int)czf;
    return (cz << 18) + (cy << 9) + cx;
}

// ---------------- fused init: out + byte mask + cursors ----------------
__global__ __launch_bounds__(256)
void k_init(float4* __restrict__ out4,
            uint4* __restrict__ bytes4,
            uint4* __restrict__ cur4) {
    int i = blockIdx.x * blockDim.x + threadIdx.x;
    int stride = gridDim.x * blockDim.x;
    const int n  = OUT_TOTAL / 4;
    const int c0 = COORS_OFF / 4, c1 = NP_OFF / 4;
    for (int j = i; j < n; j += stride) {
        float v = (j >= c0 && j < c1) ? -1.0f : 0.0f;
        out4[j] = make_float4(v, v, v, v);
    }
    const uint4 z = make_uint4(0u, 0u, 0u, 0u);
    const int nb = NVOX / 16;
    for (int j = i; j < nb; j += stride) bytes4[j] = z;
    const int nc = (MAXV * 4) / 16;
    for (int j = i; j < nc; j += stride) cur4[j] = z;
}

// ---------------- mark: plain byte stores (no atomics) ----------------
__device__ __forceinline__ void mark_one(float x, float y, float z,
                                         uint8_t* __restrict__ bytes) {
    int lin = compute_lin(x, y, z);
    if (lin >= 0) bytes[lin] = 1;
}

__global__ __launch_bounds__(256)
void k_mark(const float* __restrict__ pts, int P,
            uint8_t* __restrict__ bytes) {
    int tid = blockIdx.x * blockDim.x + threadIdx.x;
    int base = tid * 8;
    if (base + 7 < P) {
        const float4* p4 = (const float4*)pts;
        float4 a = p4[tid*6+0], b = p4[tid*6+1], c = p4[tid*6+2];
        float4 d = p4[tid*6+3], e = p4[tid*6+4], f = p4[tid*6+5];
        mark_one(a.x, a.y, a.z, bytes);
        mark_one(a.w, b.x, b.y, bytes);
        mark_one(b.z, b.w, c.x, bytes);
        mark_one(c.y, c.z, c.w, bytes);
        mark_one(d.x, d.y, d.z, bytes);
        mark_one(d.w, e.x, e.y, bytes);
        mark_one(e.z, e.w, f.x, bytes);
        mark_one(f.y, f.z, f.w, bytes);
    } else {
        for (int i = base; i < P; ++i)
            mark_one(pts[3*i], pts[3*i+1], pts[3*i+2], bytes);
    }
}

// ---------------- pack bytes -> bitmask words + per-block sums ----------------
// 60 blocks x 256 threads, 4 words (=256 bytes) per thread
__global__ __launch_bounds__(256)
void k_pack(const uint8_t* __restrict__ bytes,
            unsigned long long* __restrict__ bm,
            uint32_t* __restrict__ blockSums) {
    __shared__ uint32_t sh[256];
    int t = threadIdx.x, b = blockIdx.x;
    int w0 = b * 1024 + t * 4;
    const unsigned long long* b64 = (const unsigned long long*)bytes;
    uint32_t s = 0;
#pragma unroll
    for (int k = 0; k < 4; ++k) {
        int w = w0 + k;
        unsigned long long word = 0;
#pragma unroll
        for (int j = 0; j < 8; ++j) {
            unsigned long long v = b64[w * 8 + j];   // 8 bytes, each 0 or 1
            unsigned long long m = (v * 0x0102040810204080ull) >> 56;
            word |= m << (8 * j);
        }
        bm[w] = word;
        s += (uint32_t)__popcll(word);
    }
    sh[t] = s; __syncthreads();
    for (int off = 128; off > 0; off >>= 1) {
        if (t < off) sh[t] += sh[t + off];
        __syncthreads();
    }
    if (t == 0) blockSums[b] = sh[0];
}

// ---------------- scan: fused block-offset scan + word prefixes ----------------
// 60 blocks x 256 threads; each block redundantly scans the 60 block sums.
__global__ __launch_bounds__(256)
void k_scan(const unsigned long long* __restrict__ bm,
            const uint32_t* __restrict__ blockSums,
            uint4* __restrict__ wordInfo) {
    __shared__ uint32_t sh[256];
    __shared__ uint32_t s_off;
    int t = threadIdx.x, b = blockIdx.x;

    if (t < 64) {
        uint32_t own = (t < NBLKS) ? blockSums[t] : 0u;
        uint32_t v = own;
        for (int off = 1; off < 64; off <<= 1) {
            uint32_t n = __shfl_up(v, off, 64);
            if (t >= off) v += n;
        }
        if (t == b) s_off = v - own;   // exclusive prefix of this block
    }

    int base = b * 1024 + t * 4;
    unsigned long long w0 = bm[base + 0];
    unsigned long long w1 = bm[base + 1];
    unsigned long long w2 = bm[base + 2];
    unsigned long long w3 = bm[base + 3];
    uint32_t c0 = (uint32_t)__popcll(w0);
    uint32_t c1 = (uint32_t)__popcll(w1);
    uint32_t c2 = (uint32_t)__popcll(w2);
    uint32_t c3 = (uint32_t)__popcll(w3);
    uint32_t s = c0 + c1 + c2 + c3;
    sh[t] = s; __syncthreads();
    // Hillis-Steele inclusive scan over 256 thread sums
    for (int off = 1; off < 256; off <<= 1) {
        uint32_t v = (t >= off) ? sh[t - off] : 0u;
        __syncthreads();
        sh[t] += v;
        __syncthreads();
    }
    uint32_t excl = sh[t] - s + s_off;

    uint4 wi;
    wi.x = (uint32_t)w0; wi.y = (uint32_t)(w0 >> 32); wi.z = excl;              wi.w = 0;
    wordInfo[base + 0] = wi;
    wi.x = (uint32_t)w1; wi.y = (uint32_t)(w1 >> 32); wi.z = excl + c0;         wi.w = 0;
    wordInfo[base + 1] = wi;
    wi.x = (uint32_t)w2; wi.y = (uint32_t)(w2 >> 32); wi.z = excl + c0 + c1;    wi.w = 0;
    wordInfo[base + 2] = wi;
    wi.x = (uint32_t)w3; wi.y = (uint32_t)(w3 >> 32); wi.z = excl + c0 + c1 + c2; wi.w = 0;
    wordInfo[base + 3] = wi;
}

// ---------------- emit ----------------
__device__ __forceinline__ void emit_one(float x, float y, float z,
                                         const uint4* __restrict__ wordInfo,
                                         uint32_t* __restrict__ cursors,
                                         float* __restrict__ out) {
    int lin = compute_lin(x, y, z);
    if (lin < 0) return;
    int w = lin >> 6, bit = lin & 63;
    uint4 wi = wordInfo[w];   // single 16B gather: {word_lo, word_hi, prefix}
    unsigned long long word = ((unsigned long long)wi.y << 32) | wi.x;
    uint32_t slot = wi.z + (uint32_t)__popcll(word & ((1ull << bit) - 1ull));
    if (slot >= MAXV) return;   // only the 120000 smallest-lin voxels kept
    uint32_t r = atomicAdd(&cursors[slot], 1u);
    if (r < MAXP) {
        float* vp = out + (size_t)slot * (MAXP * 3) + (size_t)r * 3;
        vp[0] = x; vp[1] = y; vp[2] = z;
    }
    if (r == 0) {
        int cz = lin >> 18, cy = (lin >> 9) & 511, cx = lin & 511;
        float* cp = out + COORS_OFF + (size_t)slot * 3;
        cp[0] = (float)cz; cp[1] = (float)cy; cp[2] = (float)cx;  // (z,y,x)
    }
}

__global__ __launch_bounds__(256)
void k_emit(const float* __restrict__ pts, int P,
            const uint4* __restrict__ wordInfo,
            uint32_t* __restrict__ cursors,
            float* __restrict__ out) {
    int tid = blockIdx.x * blockDim.x + threadIdx.x;
    int base = tid * 8;
    if (base + 7 < P) {
        const float4* p4 = (const float4*)pts;
        float4 a = p4[tid*6+0], b = p4[tid*6+1], c = p4[tid*6+2];
        float4 d = p4[tid*6+3], e = p4[tid*6+4], f = p4[tid*6+5];
        emit_one(a.x, a.y, a.z, wordInfo, cursors, out);
        emit_one(a.w, b.x, b.y, wordInfo, cursors, out);
        emit_one(b.z, b.w, c.x, wordInfo, cursors, out);
        emit_one(c.y, c.z, c.w, wordInfo, cursors, out);
        emit_one(d.x, d.y, d.z, wordInfo, cursors, out);
        emit_one(d.w, e.x, e.y, wordInfo, cursors, out);
        emit_one(e.z, e.w, f.x, wordInfo, cursors, out);
        emit_one(f.y, f.z, f.w, wordInfo, cursors, out);
    } else {
        for (int i = base; i < P; ++i)
            emit_one(pts[3*i], pts[3*i+1], pts[3*i+2], wordInfo, cursors, out);
    }
}

__global__ __launch_bounds__(256)
void k_numpoints(const uint32_t* __restrict__ cursors,
                 float* __restrict__ out) {
    int v = blockIdx.x * blockDim.x + threadIdx.x;
    if (v >= MAXV) return;
    uint32_t c = cursors[v];
    if (c > MAXP) c = MAXP;
    out[NP_OFF + v] = (float)c;
}

// ---------------- launch ----------------
extern "C" void kernel_launch(void* const* d_in, const int* in_sizes, int n_in,
                              void* d_out, int out_size, void* d_ws, size_t ws_size,
                              hipStream_t stream) {
    const float* pts = (const float*)d_in[0];
    const int P = in_sizes[0] / 3;  // 2,097,152
    float* out = (float*)d_out;
    char* ws = (char*)d_ws;

    uint8_t* bytes           = (uint8_t*)(ws + 0);
    unsigned long long* bm   = (unsigned long long*)(ws + BM_OFF_B);
    uint32_t* blockSums      = (uint32_t*)(ws + BS_OFF_B);
    uint4*    wordInfo       = (uint4*)(ws + WI_OFF_B);
    uint32_t* cursors        = (uint32_t*)(ws + CUR_OFF_B);

    const int ptThreads = (P + 7) / 8;
    const int ptBlocks  = (ptThreads + 255) / 256;   // 1024 for P=2M

    k_init<<<2048, 256, 0, stream>>>((float4*)out, (uint4*)bytes, (uint4*)cursors);
    k_mark<<<ptBlocks, 256, 0, stream>>>(pts, P, bytes);
    k_pack<<<NBLKS, 256, 0, stream>>>(bytes, bm, blockSums);
    k_scan<<<NBLKS, 256, 0, stream>>>(bm, blockSums, wordInfo);
    k_emit<<<ptBlocks, 256, 0, stream>>>(pts, P, wordInfo, cursors, out);
    k_numpoints<<<(MAXV + 255) / 256, 256, 0, stream>>>(cursors, out);
}

// Round 4
// 64.678 us; speedup vs baseline: 1.8347x; 1.0349x over previous
//
#include <hip/hip_runtime.h>
#include <cstdint>
#include <cstddef>

// ---------------- problem constants ----------------
#define GXD 512
#define GYD 512
#define GZD 15
#define NVOX (GXD * GYD * GZD)   // 3,932,160
#define NWORDS (NVOX / 64)       // 61,440
#define NBLKS  60                // pack blocks: NWORDS / 1024
#define PS_BLKS 360              // total packscan blocks (rest only zero out[])
#define MAXV 120000
#define MAXP 32

#define VOX_FLOATS (MAXV * MAXP * 3)     // 11,520,000
#define COORS_OFF  VOX_FLOATS
#define NP_OFF     (VOX_FLOATS + MAXV*3) // 11,880,000
#define OUT_TOTAL  (NP_OFF + MAXV)       // 12,000,000

// ---------------- workspace layout (bytes) ----------------
// bytes u8[NVOX]          @ 0
// cursors u32[MAXV]       @ NVOX
// flagSum u32[64]         @ +
// wordInfo uint4[NWORDS]  @ +
#define CUR_OFF_B  NVOX                       // 3,932,160
#define FS_OFF_B   (CUR_OFF_B + MAXV * 4)     // 4,412,160
#define WI_OFF_B   (FS_OFF_B + 256)           // 4,412,416 (16B aligned)
#define WS_BYTES   (WI_OFF_B + NWORDS * 16)   // 5,395,456

#define FLAG_VALID 0x80000000u

// lin -> coords:  GX*GY = 2^18, GX = 2^9
__device__ __forceinline__ int compute_lin(float x, float y, float z) {
    if (isnan(x) || isnan(y) || isnan(z)) return -1;
    // EXACT reference numerics: f32 subtract, f32 IEEE divide, floorf
    float cxf = floorf((x - (-51.2f)) / 0.2f);
    float cyf = floorf((y - (-51.2f)) / 0.2f);
    float czf = floorf((z - (-3.0f)) / 0.4f);
    if (!(cxf >= 0.0f && cxf < 512.0f &&
          cyf >= 0.0f && cyf < 512.0f &&
          czf >= 0.0f && czf < 15.0f)) return -1;
    int cx = (int)cxf, cy = (int)cyf, cz = (int)czf;
    return (cz << 18) + (cy << 9) + cx;
}

// ---------------- init: byte mask + cursors + flags (small, ~4.4 MB) --------
__global__ __launch_bounds__(256)
void k_init0(uint4* __restrict__ bytes4, uint4* __restrict__ cur4,
             uint4* __restrict__ flag4) {
    int i = blockIdx.x * blockDim.x + threadIdx.x;
    int stride = gridDim.x * blockDim.x;
    const uint4 z = make_uint4(0u, 0u, 0u, 0u);
    const int nb = NVOX / 16;
    for (int j = i; j < nb; j += stride) bytes4[j] = z;
    const int nc = (MAXV * 4) / 16;
    for (int j = i; j < nc; j += stride) cur4[j] = z;
    if (i < 16) flag4[i] = z;
}

// ---------------- mark: plain byte stores (no atomics) ----------------
__device__ __forceinline__ void mark_one(float x, float y, float z,
                                         uint8_t* __restrict__ bytes) {
    int lin = compute_lin(x, y, z);
    if (lin >= 0) bytes[lin] = 1;
}

__global__ __launch_bounds__(256)
void k_mark(const float* __restrict__ pts, int P,
            uint8_t* __restrict__ bytes) {
    int tid = blockIdx.x * blockDim.x + threadIdx.x;
    int base = tid * 8;
    if (base + 7 < P) {
        const float4* p4 = (const float4*)pts;
        float4 a = p4[tid*6+0], b = p4[tid*6+1], c = p4[tid*6+2];
        float4 d = p4[tid*6+3], e = p4[tid*6+4], f = p4[tid*6+5];
        mark_one(a.x, a.y, a.z, bytes);
        mark_one(a.w, b.x, b.y, bytes);
        mark_one(b.z, b.w, c.x, bytes);
        mark_one(c.y, c.z, c.w, bytes);
        mark_one(d.x, d.y, d.z, bytes);
        mark_one(d.w, e.x, e.y, bytes);
        mark_one(e.z, e.w, f.x, bytes);
        mark_one(f.y, f.z, f.w, bytes);
    } else {
        for (int i = base; i < P; ++i)
            mark_one(pts[3*i], pts[3*i+1], pts[3*i+2], bytes);
    }
}

// ---------------- packscan: pack bits + publish/spin scan + zero out[] ------
// Blocks 0..NBLKS-1: pack 1024 words each, block-scan, publish total,
//   zero out[] slice (hides spin), spin on predecessors, write wordInfo.
// Blocks NBLKS..PS_BLKS-1: only zero their out[] slice.
__global__ __launch_bounds__(256)
void k_packscan(const uint8_t* __restrict__ bytes,
                uint32_t* __restrict__ flagSum,
                uint4* __restrict__ wordInfo,
                float4* __restrict__ out4) {
    __shared__ uint32_t sh[256];
    __shared__ uint32_t s_base;
    int t = threadIdx.x, b = blockIdx.x;

    unsigned long long w0 = 0, w1 = 0, w2 = 0, w3 = 0;
    uint32_t c0 = 0, c1 = 0, c2 = 0, s = 0;
    int wbase = 0;

    if (b < NBLKS) {
        wbase = b * 1024 + t * 4;
        const unsigned long long* b64 = (const unsigned long long*)bytes;
        unsigned long long w[4];
#pragma unroll
        for (int k = 0; k < 4; ++k) {
            unsigned long long word = 0;
#pragma unroll
            for (int j = 0; j < 8; ++j) {
                unsigned long long v = b64[(wbase + k) * 8 + j]; // 8 bytes of 0/1
                unsigned long long m = (v * 0x0102040810204080ull) >> 56;
                word |= m << (8 * j);
            }
            w[k] = word;
        }
        w0 = w[0]; w1 = w[1]; w2 = w[2]; w3 = w[3];
        c0 = (uint32_t)__popcll(w0);
        c1 = (uint32_t)__popcll(w1);
        c2 = (uint32_t)__popcll(w2);
        s = c0 + c1 + c2 + (uint32_t)__popcll(w3);
        sh[t] = s;
        __syncthreads();
        // Hillis-Steele inclusive scan over 256 thread sums
        for (int off = 1; off < 256; off <<= 1) {
            uint32_t v = (t >= off) ? sh[t - off] : 0u;
            __syncthreads();
            sh[t] += v;
            __syncthreads();
        }
        if (t == 0)  // publish block total (flag and payload share the word)
            atomicExch(&flagSum[b], sh[255] | FLAG_VALID);
    }

    // ---- zero out[] slice (all blocks) — hides the spin below ----
    {
        const int n  = OUT_TOTAL / 4;             // 3,000,000
        const int c0i = COORS_OFF / 4, c1i = NP_OFF / 4;
        const int chunk = (n + PS_BLKS - 1) / PS_BLKS;
        int lo = b * chunk;
        int hi = lo + chunk; if (hi > n) hi = n;
        for (int j = lo + t; j < hi; j += 256) {
            float v = (j >= c0i && j < c1i) ? -1.0f : 0.0f;
            out4[j] = make_float4(v, v, v, v);
        }
    }

    if (b >= NBLKS) return;

    // ---- spin-wait for predecessor block sums; wave-parallel ----
    if (t < 64) {
        uint32_t v = 0;
        if (t < b) {
            uint32_t f;
            do { f = atomicOr(&flagSum[t], 0u); } while (!(f & FLAG_VALID));
            v = f & 0x7FFFFFFFu;
        }
        for (int off = 32; off > 0; off >>= 1) v += __shfl_xor(v, off, 64);
        if (t == 0) s_base = v;
    }
    __syncthreads();

    uint32_t excl = sh[t] - s + s_base;

    uint4 wi;
    wi.x = (uint32_t)w0; wi.y = (uint32_t)(w0 >> 32); wi.z = excl;               wi.w = 0;
    wordInfo[wbase + 0] = wi;
    wi.x = (uint32_t)w1; wi.y = (uint32_t)(w1 >> 32); wi.z = excl + c0;          wi.w = 0;
    wordInfo[wbase + 1] = wi;
    wi.x = (uint32_t)w2; wi.y = (uint32_t)(w2 >> 32); wi.z = excl + c0 + c1;     wi.w = 0;
    wordInfo[wbase + 2] = wi;
    wi.x = (uint32_t)w3; wi.y = (uint32_t)(w3 >> 32); wi.z = excl + c0 + c1 + c2; wi.w = 0;
    wordInfo[wbase + 3] = wi;
}

// ---------------- emit (fused num_points via float-bit atomicMax) -----------
__device__ __forceinline__ void emit_one(float x, float y, float z,
                                         const uint4* __restrict__ wordInfo,
                                         uint32_t* __restrict__ cursors,
                                         float* __restrict__ out) {
    int lin = compute_lin(x, y, z);
    if (lin < 0) return;
    int w = lin >> 6, bit = lin & 63;
    uint4 wi = wordInfo[w];   // single 16B gather: {word_lo, word_hi, prefix}
    unsigned long long word = ((unsigned long long)wi.y << 32) | wi.x;
    uint32_t slot = wi.z + (uint32_t)__popcll(word & ((1ull << bit) - 1ull));
    if (slot >= MAXV) return;   // only the 120000 smallest-lin voxels kept
    uint32_t r = atomicAdd(&cursors[slot], 1u);
    if (r < MAXP) {
        float* vp = out + (size_t)slot * (MAXP * 3) + (size_t)r * 3;
        vp[0] = x; vp[1] = y; vp[2] = z;
        // num_points = max over (r+1); nonneg float bit pattern orders by value
        uint32_t* np = (uint32_t*)(out + NP_OFF);
        atomicMax(&np[slot], __float_as_uint((float)(r + 1)));
    }
    if (r == 0) {
        int cz = lin >> 18, cy = (lin >> 9) & 511, cx = lin & 511;
        float* cp = out + COORS_OFF + (size_t)slot * 3;
        cp[0] = (float)cz; cp[1] = (float)cy; cp[2] = (float)cx;  // (z,y,x)
    }
}

__global__ __launch_bounds__(256)
void k_emit(const float* __restrict__ pts, int P,
            const uint4* __restrict__ wordInfo,
            uint32_t* __restrict__ cursors,
            float* __restrict__ out) {
    int tid = blockIdx.x * blockDim.x + threadIdx.x;
    int base = tid * 8;
    if (base + 7 < P) {
        const float4* p4 = (const float4*)pts;
        float4 a = p4[tid*6+0], b = p4[tid*6+1], c = p4[tid*6+2];
        float4 d = p4[tid*6+3], e = p4[tid*6+4], f = p4[tid*6+5];
        emit_one(a.x, a.y, a.z, wordInfo, cursors, out);
        emit_one(a.w, b.x, b.y, wordInfo, cursors, out);
        emit_one(b.z, b.w, c.x, wordInfo, cursors, out);
        emit_one(c.y, c.z, c.w, wordInfo, cursors, out);
        emit_one(d.x, d.y, d.z, wordInfo, cursors, out);
        emit_one(d.w, e.x, e.y, wordInfo, cursors, out);
        emit_one(e.z, e.w, f.x, wordInfo, cursors, out);
        emit_one(f.y, f.z, f.w, wordInfo, cursors, out);
    } else {
        for (int i = base; i < P; ++i)
            emit_one(pts[3*i], pts[3*i+1], pts[3*i+2], wordInfo, cursors, out);
    }
}

// ---------------- launch ----------------
extern "C" void kernel_launch(void* const* d_in, const int* in_sizes, int n_in,
                              void* d_out, int out_size, void* d_ws, size_t ws_size,
                              hipStream_t stream) {
    const float* pts = (const float*)d_in[0];
    const int P = in_sizes[0] / 3;  // 2,097,152
    float* out = (float*)d_out;
    char* ws = (char*)d_ws;

    uint8_t*  bytes    = (uint8_t*)(ws + 0);
    uint32_t* cursors  = (uint32_t*)(ws + CUR_OFF_B);
    uint32_t* flagSum  = (uint32_t*)(ws + FS_OFF_B);
    uint4*    wordInfo = (uint4*)(ws + WI_OFF_B);

    const int ptThreads = (P + 7) / 8;
    const int ptBlocks  = (ptThreads + 255) / 256;   // 1024 for P=2M

    k_init0<<<512, 256, 0, stream>>>((uint4*)bytes, (uint4*)cursors,
                                     (uint4*)flagSum);
    k_mark<<<ptBlocks, 256, 0, stream>>>(pts, P, bytes);
    k_packscan<<<PS_BLKS, 256, 0, stream>>>(bytes, flagSum, wordInfo,
                                            (float4*)out);
    k_emit<<<ptBlocks, 256, 0, stream>>>(pts, P, wordInfo, cursors, out);
}